// Round 13
// baseline (132.527 us; speedup 1.0000x reference)
//
#include <hip/hip_runtime.h>
#include <hip/hip_fp16.h>
#include <math.h>

#define NN 1024

typedef _Float16 half8 __attribute__((ext_vector_type(8)));
typedef float f32x4 __attribute__((ext_vector_type(4)));

union H8U { uint4 u; half8 h; };

__device__ __forceinline__ unsigned short h_bits(float x) {
    _Float16 h = (_Float16)x;          // RNE
    unsigned short b;
    __builtin_memcpy(&b, &h, 2);
    return b;
}

// ---- prep: blocks [0,512): A' = z_c@W1c + b1 -> fp16 frag-order Aph;
//            B = z_d@W1d -> fp16 frag-order Bph.
//            blocks [512,514): W2 -> fp16 MFMA frag layout W2h, zero Srow.
__global__ void prep_kernel(const float* __restrict__ z_c, const float* __restrict__ z_d,
                            const float* __restrict__ W1, const float* __restrict__ b1,
                            const float* __restrict__ W2,
                            unsigned short* __restrict__ Aph,
                            unsigned short* __restrict__ Bph,
                            uint4* __restrict__ W2h,
                            float* __restrict__ Srow) {
    if (blockIdx.x < 512) {
        int t = blockIdx.x * 256 + threadIdx.x;
        int sel = t >> 16;            // 0 -> A', 1 -> B
        int idx = t & 0xffff;
        int n = idx >> 6, h = idx & 63;
        const float* z = (sel ? z_d : z_c) + n * 64;
        const float* w = W1 + (sel ? 4096 : 0) + h;   // W1 (128,64) row-major
        float a0 = sel ? 0.f : b1[h], a1 = 0.f;
        #pragma unroll
        for (int k = 0; k < 64; k += 2) {
            a0 = fmaf(z[k],     w[k * 64],       a0);
            a1 = fmaf(z[k + 1], w[(k + 1) * 64], a1);
        }
        unsigned short val = h_bits(a0 + a1);   // fp32-exact matmul, one RNE to fp16
        int s = h >> 5, q = (h >> 3) & 3, e = h & 7;
        if (sel) {
            Bph[n * 64 + q * 16 + s * 8 + e] = val;
        } else {
            Aph[(n >> 4) * 1024 + (q * 16 + (n & 15)) * 16 + s * 8 + e] = val;
        }
    } else {
        int tt = (blockIdx.x - 512) * 256 + threadIdx.x;   // 0..511
        Srow[tt] = 0.f; Srow[tt + 512] = 0.f;
        int f = tt >> 6, lane = tt & 63;                   // f = s*4 + t, 8 frags
        int s = f >> 2, t4 = f & 3, q = lane >> 4, l15 = lane & 15;
        int n = t4 * 16 + l15;
        unsigned w4[4];
        #pragma unroll
        for (int p = 0; p < 4; ++p) {
            int k = s * 32 + q * 8 + 2 * p;
            unsigned lo = h_bits(W2[k * 64 + n]);
            unsigned hi = h_bits(W2[(k + 1) * 64 + n]);
            w4[p] = lo | (hi << 16);
        }
        W2h[f * 64 + lane] = make_uint4(w4[0], w4[1], w4[2], w4[3]);
    }
}

// ---- main: block = (i, quarter). 4096 blocks x 256 thr; each wave 4 j-tiles of 16.
// R12 structure byte-identical EXCEPT __launch_bounds__(256, 5): bracketing
// experiment on the unified VGPR+AGPR footprint. R7 fit at budget 128; R11
// spilled at budget ~84 -> footprint in (84, 128]. Budget here ~102:
//   fits  -> 5 waves/SIMD residency (+25% latency hiding), main ~30 -> ~25 us.
//   spill -> footprint > 100 proven; next round reverts to (256,4) and the
//            4-waves/SIMD structural ceiling is established.
__global__ void __launch_bounds__(256, 5)
main_kernel(const unsigned short* __restrict__ Aph, const unsigned short* __restrict__ Bph,
            const uint4* __restrict__ W2h,
            const float* __restrict__ b2, const float* __restrict__ Wo,
            float* __restrict__ Srow, float* __restrict__ T0row) {
    const int i       = blockIdx.x >> 2;
    const int quarter = blockIdx.x & 3;
    const int tid  = threadIdx.x;
    const int lane = tid & 63;
    const int wave = tid >> 6;
    const int l15  = lane & 15;
    const int q    = lane >> 4;

    __shared__ uint4 sW[512];      // W2 frag bits, 8 KB
    __shared__ float sb2[64];      // b2, 256 B
    __shared__ float sWo[64];      // Wo, 256 B

    // cooperative stage: 2 x 16B VMEM per thread + tiny b2/Wo copy
    sW[tid]       = W2h[tid];
    sW[tid + 256] = W2h[tid + 256];
    if (tid < 64)                  sb2[tid]      = b2[tid];
    else if (tid < 128)            sWo[tid - 64] = Wo[tid - 64];
    __syncthreads();

    // W2 fragments from LDS: 8 ds_read_b128, lane-contiguous (conflict-free)
    half8 W[2][4];   // [s][t]
    #pragma unroll
    for (int f = 0; f < 8; ++f) {
        H8U u; u.u = sW[f * 64 + lane];
        W[f >> 2][f & 3] = u.h;
    }

    // B_i per-lane slice (fp16 frag order): 2 dwordx4 = 16 halves, k = s*32+q*8+e
    H8U cb0, cb1;
    {
        const uint4* bp = (const uint4*)(Bph + i * 64 + q * 16);
        cb0.u = bp[0];
        cb1.u = bp[1];
    }

    // b2 folded into acc init; Wo per-lane, element (t,r) is h = t*16 + q*4 + r
    f32x4 b2v[4];
    float wov[4][4];
    #pragma unroll
    for (int t = 0; t < 4; ++t) {
        float4 bt = *(const float4*)(sb2 + t * 16 + q * 4);
        float4 wt = *(const float4*)(sWo + t * 16 + q * 4);
        b2v[t] = (f32x4){bt.x, bt.y, bt.z, bt.w};
        wov[t][0] = wt.x; wov[t][1] = wt.y; wov[t][2] = wt.z; wov[t][3] = wt.w;
    }

    const int tbase = quarter * 16 + wave * 4;
    const unsigned short* ap = Aph + tbase * 1024 + lane * 16;

    H8U x0, x1;
    x0.u = ((const uint4*)ap)[0];
    x1.u = ((const uint4*)ap)[1];

    const half8 zero = {0, 0, 0, 0, 0, 0, 0, 0};
    float psum[4];
    float sacc = 0.f;

    #pragma unroll
    for (int tile = 0; tile < 4; ++tile) {
        half8 a0 = __builtin_elementwise_max(x0.h + cb0.h, zero);   // k 0..31
        half8 a1 = __builtin_elementwise_max(x1.h + cb1.h, zero);   // k 32..63
        if (tile < 3) {
            const uint4* nx = (const uint4*)(ap + (tile + 1) * 1024);
            x0.u = nx[0];
            x1.u = nx[1];
        }

        f32x4 acc[4];
        #pragma unroll
        for (int t = 0; t < 4; ++t) acc[t] = b2v[t];
        #pragma unroll
        for (int t = 0; t < 4; ++t) {
            acc[t] = __builtin_amdgcn_mfma_f32_16x16x32_f16(W[0][t], a0, acc[t], 0, 0, 0);
            acc[t] = __builtin_amdgcn_mfma_f32_16x16x32_f16(W[1][t], a1, acc[t], 0, 0, 0);
        }

        float p0 = 0.f, p1 = 0.f, p2 = 0.f, p3 = 0.f;
        #pragma unroll
        for (int t = 0; t < 4; ++t) {
            p0 = fmaf(fmaxf(acc[t][0], 0.f), wov[t][0], p0);
            p1 = fmaf(fmaxf(acc[t][1], 0.f), wov[t][1], p1);
            p2 = fmaf(fmaxf(acc[t][2], 0.f), wov[t][2], p2);
            p3 = fmaf(fmaxf(acc[t][3], 0.f), wov[t][3], p3);
        }
        psum[tile] = (p0 + p1) + (p2 + p3);
    }

    // Epilogue: 4 independent reduce/exp chains
    #pragma unroll
    for (int tile = 0; tile < 4; ++tile) {
        float ps = psum[tile];
        ps += __shfl_xor(ps, 16);
        ps += __shfl_xor(ps, 32);   // T1[j], replicated over the 4 q-groups
        const int j = (tbase + tile) * 16 + l15;
        if (j == i && q == 0) T0row[i] = ps;   // diagonal: exactly one writer
        sacc += __expf(ps);
    }
    // reduce over l15 only (q-groups are exact replicas -> exact sum)
    sacc += __shfl_xor(sacc, 1);
    sacc += __shfl_xor(sacc, 2);
    sacc += __shfl_xor(sacc, 4);
    sacc += __shfl_xor(sacc, 8);
    if (lane == 0) atomicAdd(&Srow[i], sacc);   // plain device atomic, no ordering
}

// ---- combine+finish: 1 block x 1024 thr. bound = mean(T0) - (mean(log Srow) - ln N)
__global__ void __launch_bounds__(1024)
combine_finish(const float* __restrict__ Srow, const float* __restrict__ T0row,
               float* __restrict__ out) {
    int i = threadIdx.x;
    float l  = logf(Srow[i]);
    float t0 = T0row[i];
    #pragma unroll
    for (int off = 1; off < 64; off <<= 1) {
        l  += __shfl_xor(l, off);
        t0 += __shfl_xor(t0, off);
    }
    __shared__ float sl[16], st[16];
    int w = threadIdx.x >> 6;
    if ((threadIdx.x & 63) == 0) { sl[w] = l; st[w] = t0; }
    __syncthreads();
    if (threadIdx.x == 0) {
        float L = 0.f, T = 0.f;
        #pragma unroll
        for (int k = 0; k < 16; ++k) { L += sl[k]; T += st[k]; }
        out[0] = (T - L) * (1.0f / 1024.0f) + 6.9314718055994531f;
    }
}

extern "C" void kernel_launch(void* const* d_in, const int* in_sizes, int n_in,
                              void* d_out, int out_size, void* d_ws, size_t ws_size,
                              hipStream_t stream) {
    const float* z_c = (const float*)d_in[0];
    const float* z_d = (const float*)d_in[1];
    const float* W1  = (const float*)d_in[2];
    const float* b1  = (const float*)d_in[3];
    const float* W2  = (const float*)d_in[4];
    const float* b2  = (const float*)d_in[5];
    const float* Wo  = (const float*)d_in[6];
    // d_in[7] = bo: shifts T0.mean and every LSE equally -> cancels; omitted.
    float* out   = (float*)d_out;

    unsigned short* Aph = (unsigned short*)d_ws;   // 65536 fp16 (128 KB), frag-order
    unsigned short* Bph = Aph + NN * 64;           // 65536 fp16 (128 KB), frag-order
    uint4* W2h   = (uint4*)(Bph + NN * 64);        // 512 uint4 (8 KB)
    float* Srow  = (float*)(W2h + 512);            // 1024 fp32
    float* T0row = Srow + NN;                      // 1024 fp32

    prep_kernel<<<514, 256, 0, stream>>>(z_c, z_d, W1, b1, W2, Aph, Bph, W2h, Srow);
    main_kernel<<<4096, 256, 0, stream>>>(Aph, Bph, W2h, b2, Wo, Srow, T0row);
    combine_finish<<<1, 1024, 0, stream>>>(Srow, T0row, out);
}

// Round 14
// 92.439 us; speedup vs baseline: 1.4337x; 1.4337x over previous
//
#include <hip/hip_runtime.h>
#include <hip/hip_fp16.h>
#include <math.h>

#define NN 1024

typedef _Float16 half8 __attribute__((ext_vector_type(8)));
typedef float f32x4 __attribute__((ext_vector_type(4)));

union H8U { uint4 u; half8 h; };

__device__ __forceinline__ unsigned short h_bits(float x) {
    _Float16 h = (_Float16)x;          // RNE
    unsigned short b;
    __builtin_memcpy(&b, &h, 2);
    return b;
}

// ---- prep: blocks [0,512): A' = z_c@W1c + b1 -> fp16 frag-order Aph;
//            B = z_d@W1d -> fp16 frag-order Bph.
//            blocks [512,514): W2 -> fp16 MFMA frag layout W2h, zero Srow.
__global__ void prep_kernel(const float* __restrict__ z_c, const float* __restrict__ z_d,
                            const float* __restrict__ W1, const float* __restrict__ b1,
                            const float* __restrict__ W2,
                            unsigned short* __restrict__ Aph,
                            unsigned short* __restrict__ Bph,
                            uint4* __restrict__ W2h,
                            float* __restrict__ Srow) {
    if (blockIdx.x < 512) {
        int t = blockIdx.x * 256 + threadIdx.x;
        int sel = t >> 16;            // 0 -> A', 1 -> B
        int idx = t & 0xffff;
        int n = idx >> 6, h = idx & 63;
        const float* z = (sel ? z_d : z_c) + n * 64;
        const float* w = W1 + (sel ? 4096 : 0) + h;   // W1 (128,64) row-major
        float a0 = sel ? 0.f : b1[h], a1 = 0.f;
        #pragma unroll
        for (int k = 0; k < 64; k += 2) {
            a0 = fmaf(z[k],     w[k * 64],       a0);
            a1 = fmaf(z[k + 1], w[(k + 1) * 64], a1);
        }
        unsigned short val = h_bits(a0 + a1);   // fp32-exact matmul, one RNE to fp16
        int s = h >> 5, q = (h >> 3) & 3, e = h & 7;
        if (sel) {
            Bph[n * 64 + q * 16 + s * 8 + e] = val;
        } else {
            Aph[(n >> 4) * 1024 + (q * 16 + (n & 15)) * 16 + s * 8 + e] = val;
        }
    } else {
        int tt = (blockIdx.x - 512) * 256 + threadIdx.x;   // 0..511
        Srow[tt] = 0.f; Srow[tt + 512] = 0.f;
        int f = tt >> 6, lane = tt & 63;                   // f = s*4 + t, 8 frags
        int s = f >> 2, t4 = f & 3, q = lane >> 4, l15 = lane & 15;
        int n = t4 * 16 + l15;
        unsigned w4[4];
        #pragma unroll
        for (int p = 0; p < 4; ++p) {
            int k = s * 32 + q * 8 + 2 * p;
            unsigned lo = h_bits(W2[k * 64 + n]);
            unsigned hi = h_bits(W2[(k + 1) * 64 + n]);
            w4[p] = lo | (hi << 16);
        }
        W2h[f * 64 + lane] = make_uint4(w4[0], w4[1], w4[2], w4[3]);
    }
}

// ---- main: 4096 blocks x 256 thr; block = (quarter, i) with quarter in the HIGH
// bits (consecutively-dispatched blocks share the same Aph quarter and adjacent
// Bph lines -> L1/L2 locality). Each wave: 4 j-tiles of 16. fp16 MFMA pipeline,
// LDS-staged W2/b2/Wo.
// __launch_bounds__(256, 4) is LOAD-BEARING: unified VGPR+AGPR footprint measured
// in (102, 128] (R7 fits at budget 128; R13 spills at 102; R11 spills at 85).
// Any min-waves bound > 4 forces a 100+ MB scratch spill. Do not raise.
// No fences / ordered atomics anywhere (R3, R10: TCC cache-maintenance storms).
__global__ void __launch_bounds__(256, 4)
main_kernel(const unsigned short* __restrict__ Aph, const unsigned short* __restrict__ Bph,
            const uint4* __restrict__ W2h,
            const float* __restrict__ b2, const float* __restrict__ Wo,
            float* __restrict__ Srow, float* __restrict__ T0row) {
    const int quarter = blockIdx.x >> 10;
    const int i       = blockIdx.x & 1023;
    const int tid  = threadIdx.x;
    const int lane = tid & 63;
    const int wave = tid >> 6;
    const int l15  = lane & 15;
    const int q    = lane >> 4;

    __shared__ uint4 sW[512];      // W2 frag bits, 8 KB
    __shared__ float sb2[64];      // b2, 256 B
    __shared__ float sWo[64];      // Wo, 256 B

    // cooperative stage: 2 x 16B VMEM per thread + tiny b2/Wo copy
    sW[tid]       = W2h[tid];
    sW[tid + 256] = W2h[tid + 256];
    if (tid < 64)                  sb2[tid]      = b2[tid];
    else if (tid < 128)            sWo[tid - 64] = Wo[tid - 64];
    __syncthreads();

    // W2 fragments from LDS: 8 ds_read_b128, lane-contiguous (conflict-free)
    half8 W[2][4];   // [s][t]
    #pragma unroll
    for (int f = 0; f < 8; ++f) {
        H8U u; u.u = sW[f * 64 + lane];
        W[f >> 2][f & 3] = u.h;
    }

    // B_i per-lane slice (fp16 frag order): 2 dwordx4 = 16 halves, k = s*32+q*8+e
    H8U cb0, cb1;
    {
        const uint4* bp = (const uint4*)(Bph + i * 64 + q * 16);
        cb0.u = bp[0];
        cb1.u = bp[1];
    }

    // b2 folded into acc init; Wo per-lane, element (t,r) is h = t*16 + q*4 + r
    f32x4 b2v[4];
    float wov[4][4];
    #pragma unroll
    for (int t = 0; t < 4; ++t) {
        float4 bt = *(const float4*)(sb2 + t * 16 + q * 4);
        float4 wt = *(const float4*)(sWo + t * 16 + q * 4);
        b2v[t] = (f32x4){bt.x, bt.y, bt.z, bt.w};
        wov[t][0] = wt.x; wov[t][1] = wt.y; wov[t][2] = wt.z; wov[t][3] = wt.w;
    }

    const int tbase = quarter * 16 + wave * 4;
    const unsigned short* ap = Aph + tbase * 1024 + lane * 16;

    H8U x0, x1;
    x0.u = ((const uint4*)ap)[0];
    x1.u = ((const uint4*)ap)[1];

    const half8 zero = {0, 0, 0, 0, 0, 0, 0, 0};
    float psum[4];
    float sacc = 0.f;

    #pragma unroll
    for (int tile = 0; tile < 4; ++tile) {
        half8 a0 = __builtin_elementwise_max(x0.h + cb0.h, zero);   // k 0..31
        half8 a1 = __builtin_elementwise_max(x1.h + cb1.h, zero);   // k 32..63
        if (tile < 3) {
            const uint4* nx = (const uint4*)(ap + (tile + 1) * 1024);
            x0.u = nx[0];
            x1.u = nx[1];
        }

        f32x4 acc[4];
        #pragma unroll
        for (int t = 0; t < 4; ++t) acc[t] = b2v[t];
        #pragma unroll
        for (int t = 0; t < 4; ++t) {
            acc[t] = __builtin_amdgcn_mfma_f32_16x16x32_f16(W[0][t], a0, acc[t], 0, 0, 0);
            acc[t] = __builtin_amdgcn_mfma_f32_16x16x32_f16(W[1][t], a1, acc[t], 0, 0, 0);
        }

        float p0 = 0.f, p1 = 0.f, p2 = 0.f, p3 = 0.f;
        #pragma unroll
        for (int t = 0; t < 4; ++t) {
            p0 = fmaf(fmaxf(acc[t][0], 0.f), wov[t][0], p0);
            p1 = fmaf(fmaxf(acc[t][1], 0.f), wov[t][1], p1);
            p2 = fmaf(fmaxf(acc[t][2], 0.f), wov[t][2], p2);
            p3 = fmaf(fmaxf(acc[t][3], 0.f), wov[t][3], p3);
        }
        psum[tile] = (p0 + p1) + (p2 + p3);
    }

    // Epilogue: 4 independent reduce/exp chains
    #pragma unroll
    for (int tile = 0; tile < 4; ++tile) {
        float ps = psum[tile];
        ps += __shfl_xor(ps, 16);
        ps += __shfl_xor(ps, 32);   // T1[j], replicated over the 4 q-groups
        const int j = (tbase + tile) * 16 + l15;
        if (j == i && q == 0) T0row[i] = ps;   // diagonal: exactly one writer
        sacc += __expf(ps);
    }
    // reduce over l15 only (q-groups are exact replicas -> exact sum)
    sacc += __shfl_xor(sacc, 1);
    sacc += __shfl_xor(sacc, 2);
    sacc += __shfl_xor(sacc, 4);
    sacc += __shfl_xor(sacc, 8);
    if (lane == 0) atomicAdd(&Srow[i], sacc);   // plain device atomic, no ordering
}

// ---- combine+finish: 1 block x 1024 thr. bound = mean(T0) - (mean(log Srow) - ln N)
__global__ void __launch_bounds__(1024)
combine_finish(const float* __restrict__ Srow, const float* __restrict__ T0row,
               float* __restrict__ out) {
    int i = threadIdx.x;
    float l  = logf(Srow[i]);
    float t0 = T0row[i];
    #pragma unroll
    for (int off = 1; off < 64; off <<= 1) {
        l  += __shfl_xor(l, off);
        t0 += __shfl_xor(t0, off);
    }
    __shared__ float sl[16], st[16];
    int w = threadIdx.x >> 6;
    if ((threadIdx.x & 63) == 0) { sl[w] = l; st[w] = t0; }
    __syncthreads();
    if (threadIdx.x == 0) {
        float L = 0.f, T = 0.f;
        #pragma unroll
        for (int k = 0; k < 16; ++k) { L += sl[k]; T += st[k]; }
        out[0] = (T - L) * (1.0f / 1024.0f) + 6.9314718055994531f;
    }
}

extern "C" void kernel_launch(void* const* d_in, const int* in_sizes, int n_in,
                              void* d_out, int out_size, void* d_ws, size_t ws_size,
                              hipStream_t stream) {
    const float* z_c = (const float*)d_in[0];
    const float* z_d = (const float*)d_in[1];
    const float* W1  = (const float*)d_in[2];
    const float* b1  = (const float*)d_in[3];
    const float* W2  = (const float*)d_in[4];
    const float* b2  = (const float*)d_in[5];
    const float* Wo  = (const float*)d_in[6];
    // d_in[7] = bo: shifts T0.mean and every LSE equally -> cancels; omitted.
    float* out   = (float*)d_out;

    unsigned short* Aph = (unsigned short*)d_ws;   // 65536 fp16 (128 KB), frag-order
    unsigned short* Bph = Aph + NN * 64;           // 65536 fp16 (128 KB), frag-order
    uint4* W2h   = (uint4*)(Bph + NN * 64);        // 512 uint4 (8 KB)
    float* Srow  = (float*)(W2h + 512);            // 1024 fp32
    float* T0row = Srow + NN;                      // 1024 fp32

    prep_kernel<<<514, 256, 0, stream>>>(z_c, z_d, W1, b1, W2, Aph, Bph, W2h, Srow);
    main_kernel<<<4096, 256, 0, stream>>>(Aph, Bph, W2h, b2, Wo, Srow, T0row);
    combine_finish<<<1, 1024, 0, stream>>>(Srow, T0row, out);
}

// Round 15
// 87.948 us; speedup vs baseline: 1.5069x; 1.0511x over previous
//
#include <hip/hip_runtime.h>
#include <hip/hip_fp16.h>
#include <math.h>

#define NN 1024

typedef _Float16 half8 __attribute__((ext_vector_type(8)));
typedef float f32x4 __attribute__((ext_vector_type(4)));

union H8U { uint4 u; half8 h; };

__device__ __forceinline__ unsigned short h_bits(float x) {
    _Float16 h = (_Float16)x;          // RNE
    unsigned short b;
    __builtin_memcpy(&b, &h, 2);
    return b;
}

// ---- prep: blocks [0,512): A' = z_c@W1c + b1 -> fp16 frag-order Aph;
//            B = z_d@W1d -> fp16 frag-order Bph.
//            blocks [512,514): W2 -> fp16 MFMA frag layout W2h, zero Srow.
__global__ void prep_kernel(const float* __restrict__ z_c, const float* __restrict__ z_d,
                            const float* __restrict__ W1, const float* __restrict__ b1,
                            const float* __restrict__ W2,
                            unsigned short* __restrict__ Aph,
                            unsigned short* __restrict__ Bph,
                            uint4* __restrict__ W2h,
                            float* __restrict__ Srow) {
    if (blockIdx.x < 512) {
        int t = blockIdx.x * 256 + threadIdx.x;
        int sel = t >> 16;            // 0 -> A', 1 -> B
        int idx = t & 0xffff;
        int n = idx >> 6, h = idx & 63;
        const float* z = (sel ? z_d : z_c) + n * 64;
        const float* w = W1 + (sel ? 4096 : 0) + h;   // W1 (128,64) row-major
        float a0 = sel ? 0.f : b1[h], a1 = 0.f;
        #pragma unroll
        for (int k = 0; k < 64; k += 2) {
            a0 = fmaf(z[k],     w[k * 64],       a0);
            a1 = fmaf(z[k + 1], w[(k + 1) * 64], a1);
        }
        unsigned short val = h_bits(a0 + a1);   // fp32-exact matmul, one RNE to fp16
        int s = h >> 5, q = (h >> 3) & 3, e = h & 7;
        if (sel) {
            Bph[n * 64 + q * 16 + s * 8 + e] = val;
        } else {
            Aph[(n >> 4) * 1024 + (q * 16 + (n & 15)) * 16 + s * 8 + e] = val;
        }
    } else {
        int tt = (blockIdx.x - 512) * 256 + threadIdx.x;   // 0..511
        Srow[tt] = 0.f; Srow[tt + 512] = 0.f;
        int f = tt >> 6, lane = tt & 63;                   // f = s*4 + t, 8 frags
        int s = f >> 2, t4 = f & 3, q = lane >> 4, l15 = lane & 15;
        int n = t4 * 16 + l15;
        unsigned w4[4];
        #pragma unroll
        for (int p = 0; p < 4; ++p) {
            int k = s * 32 + q * 8 + 2 * p;
            unsigned lo = h_bits(W2[k * 64 + n]);
            unsigned hi = h_bits(W2[(k + 1) * 64 + n]);
            w4[p] = lo | (hi << 16);
        }
        W2h[f * 64 + lane] = make_uint4(w4[0], w4[1], w4[2], w4[3]);
    }
}

// ---- main: 2048 blocks x 256 thr; block = (half, i), half in the HIGH bits
// (consecutive blocks share the same 32 KB Aph half -> L1/L2 locality, per R14's
// verified swizzle win). Each wave: 8 j-tiles of 16 (amortizes the per-block
// prologue -- LDS stage + W2 frag reads + cb/b2v/wov setup -- over 2x the work
// vs R14's 4096x4; halves Bph loads and epilogue atomics).
// __launch_bounds__(256, 4) is LOAD-BEARING: unified VGPR+AGPR footprint measured
// in (102, 128] (R7 fits at budget 128; R13 spills at 102; R11 spills at 85).
// Any min-waves bound > 4 forces a 100+ MB scratch spill. Do not raise.
// No fences / ordered atomics anywhere (R3, R10: TCC cache-maintenance storms).
__global__ void __launch_bounds__(256, 4)
main_kernel(const unsigned short* __restrict__ Aph, const unsigned short* __restrict__ Bph,
            const uint4* __restrict__ W2h,
            const float* __restrict__ b2, const float* __restrict__ Wo,
            float* __restrict__ Srow, float* __restrict__ T0row) {
    const int half = blockIdx.x >> 10;
    const int i    = blockIdx.x & 1023;
    const int tid  = threadIdx.x;
    const int lane = tid & 63;
    const int wave = tid >> 6;
    const int l15  = lane & 15;
    const int q    = lane >> 4;

    __shared__ uint4 sW[512];      // W2 frag bits, 8 KB
    __shared__ float sb2[64];      // b2, 256 B
    __shared__ float sWo[64];      // Wo, 256 B

    // cooperative stage: 2 x 16B VMEM per thread + tiny b2/Wo copy
    sW[tid]       = W2h[tid];
    sW[tid + 256] = W2h[tid + 256];
    if (tid < 64)                  sb2[tid]      = b2[tid];
    else if (tid < 128)            sWo[tid - 64] = Wo[tid - 64];
    __syncthreads();

    // W2 fragments from LDS: 8 ds_read_b128, lane-contiguous (conflict-free)
    half8 W[2][4];   // [s][t]
    #pragma unroll
    for (int f = 0; f < 8; ++f) {
        H8U u; u.u = sW[f * 64 + lane];
        W[f >> 2][f & 3] = u.h;
    }

    // B_i per-lane slice (fp16 frag order): 2 dwordx4 = 16 halves, k = s*32+q*8+e
    H8U cb0, cb1;
    {
        const uint4* bp = (const uint4*)(Bph + i * 64 + q * 16);
        cb0.u = bp[0];
        cb1.u = bp[1];
    }

    // b2 folded into acc init; Wo per-lane, element (t,r) is h = t*16 + q*4 + r
    f32x4 b2v[4];
    float wov[4][4];
    #pragma unroll
    for (int t = 0; t < 4; ++t) {
        float4 bt = *(const float4*)(sb2 + t * 16 + q * 4);
        float4 wt = *(const float4*)(sWo + t * 16 + q * 4);
        b2v[t] = (f32x4){bt.x, bt.y, bt.z, bt.w};
        wov[t][0] = wt.x; wov[t][1] = wt.y; wov[t][2] = wt.z; wov[t][3] = wt.w;
    }

    const int tbase = half * 32 + wave * 8;
    const unsigned short* ap = Aph + tbase * 1024 + lane * 16;

    H8U x0, x1;
    x0.u = ((const uint4*)ap)[0];
    x1.u = ((const uint4*)ap)[1];

    const half8 zero = {0, 0, 0, 0, 0, 0, 0, 0};
    float psum[8];
    float sacc = 0.f;

    #pragma unroll
    for (int tile = 0; tile < 8; ++tile) {
        half8 a0 = __builtin_elementwise_max(x0.h + cb0.h, zero);   // k 0..31
        half8 a1 = __builtin_elementwise_max(x1.h + cb1.h, zero);   // k 32..63
        if (tile < 7) {
            const uint4* nx = (const uint4*)(ap + (tile + 1) * 1024);
            x0.u = nx[0];
            x1.u = nx[1];
        }

        f32x4 acc[4];
        #pragma unroll
        for (int t = 0; t < 4; ++t) acc[t] = b2v[t];
        #pragma unroll
        for (int t = 0; t < 4; ++t) {
            acc[t] = __builtin_amdgcn_mfma_f32_16x16x32_f16(W[0][t], a0, acc[t], 0, 0, 0);
            acc[t] = __builtin_amdgcn_mfma_f32_16x16x32_f16(W[1][t], a1, acc[t], 0, 0, 0);
        }

        float p0 = 0.f, p1 = 0.f, p2 = 0.f, p3 = 0.f;
        #pragma unroll
        for (int t = 0; t < 4; ++t) {
            p0 = fmaf(fmaxf(acc[t][0], 0.f), wov[t][0], p0);
            p1 = fmaf(fmaxf(acc[t][1], 0.f), wov[t][1], p1);
            p2 = fmaf(fmaxf(acc[t][2], 0.f), wov[t][2], p2);
            p3 = fmaf(fmaxf(acc[t][3], 0.f), wov[t][3], p3);
        }
        psum[tile] = (p0 + p1) + (p2 + p3);
    }

    // Epilogue: 8 independent reduce/exp chains
    #pragma unroll
    for (int tile = 0; tile < 8; ++tile) {
        float ps = psum[tile];
        ps += __shfl_xor(ps, 16);
        ps += __shfl_xor(ps, 32);   // T1[j], replicated over the 4 q-groups
        const int j = (tbase + tile) * 16 + l15;
        if (j == i && q == 0) T0row[i] = ps;   // diagonal: exactly one writer
        sacc += __expf(ps);
    }
    // reduce over l15 only (q-groups are exact replicas -> exact sum)
    sacc += __shfl_xor(sacc, 1);
    sacc += __shfl_xor(sacc, 2);
    sacc += __shfl_xor(sacc, 4);
    sacc += __shfl_xor(sacc, 8);
    if (lane == 0) atomicAdd(&Srow[i], sacc);   // 8 adds per i, 1024 addresses
}

// ---- combine+finish: 1 block x 1024 thr. bound = mean(T0) - (mean(log Srow) - ln N)
__global__ void __launch_bounds__(1024)
combine_finish(const float* __restrict__ Srow, const float* __restrict__ T0row,
               float* __restrict__ out) {
    int i = threadIdx.x;
    float l  = logf(Srow[i]);
    float t0 = T0row[i];
    #pragma unroll
    for (int off = 1; off < 64; off <<= 1) {
        l  += __shfl_xor(l, off);
        t0 += __shfl_xor(t0, off);
    }
    __shared__ float sl[16], st[16];
    int w = threadIdx.x >> 6;
    if ((threadIdx.x & 63) == 0) { sl[w] = l; st[w] = t0; }
    __syncthreads();
    if (threadIdx.x == 0) {
        float L = 0.f, T = 0.f;
        #pragma unroll
        for (int k = 0; k < 16; ++k) { L += sl[k]; T += st[k]; }
        out[0] = (T - L) * (1.0f / 1024.0f) + 6.9314718055994531f;
    }
}

extern "C" void kernel_launch(void* const* d_in, const int* in_sizes, int n_in,
                              void* d_out, int out_size, void* d_ws, size_t ws_size,
                              hipStream_t stream) {
    const float* z_c = (const float*)d_in[0];
    const float* z_d = (const float*)d_in[1];
    const float* W1  = (const float*)d_in[2];
    const float* b1  = (const float*)d_in[3];
    const float* W2  = (const float*)d_in[4];
    const float* b2  = (const float*)d_in[5];
    const float* Wo  = (const float*)d_in[6];
    // d_in[7] = bo: shifts T0.mean and every LSE equally -> cancels; omitted.
    float* out   = (float*)d_out;

    unsigned short* Aph = (unsigned short*)d_ws;   // 65536 fp16 (128 KB), frag-order
    unsigned short* Bph = Aph + NN * 64;           // 65536 fp16 (128 KB), frag-order
    uint4* W2h   = (uint4*)(Bph + NN * 64);        // 512 uint4 (8 KB)
    float* Srow  = (float*)(W2h + 512);            // 1024 fp32
    float* T0row = Srow + NN;                      // 1024 fp32

    prep_kernel<<<514, 256, 0, stream>>>(z_c, z_d, W1, b1, W2, Aph, Bph, W2h, Srow);
    main_kernel<<<2048, 256, 0, stream>>>(Aph, Bph, W2h, b2, Wo, Srow, T0row);
    combine_finish<<<1, 1024, 0, stream>>>(Srow, T0row, out);
}

// Round 16
// 86.400 us; speedup vs baseline: 1.5339x; 1.0179x over previous
//
#include <hip/hip_runtime.h>
#include <hip/hip_fp16.h>
#include <math.h>

#define NN 1024

typedef _Float16 half8 __attribute__((ext_vector_type(8)));
typedef float f32x4 __attribute__((ext_vector_type(4)));

union H8U { uint4 u; half8 h; };

__device__ __forceinline__ unsigned short h_bits(float x) {
    _Float16 h = (_Float16)x;          // RNE
    unsigned short b;
    __builtin_memcpy(&b, &h, 2);
    return b;
}

// ---- prep: blocks [0,512): A' = z_c@W1c + b1 -> fp16 frag-order Aph;
//            B = z_d@W1d -> fp16 frag-order Bph.
//            blocks [512,514): W2 -> fp16 MFMA frag layout W2h.
__global__ void prep_kernel(const float* __restrict__ z_c, const float* __restrict__ z_d,
                            const float* __restrict__ W1, const float* __restrict__ b1,
                            const float* __restrict__ W2,
                            unsigned short* __restrict__ Aph,
                            unsigned short* __restrict__ Bph,
                            uint4* __restrict__ W2h) {
    if (blockIdx.x < 512) {
        int t = blockIdx.x * 256 + threadIdx.x;
        int sel = t >> 16;            // 0 -> A', 1 -> B
        int idx = t & 0xffff;
        int n = idx >> 6, h = idx & 63;
        const float* z = (sel ? z_d : z_c) + n * 64;
        const float* w = W1 + (sel ? 4096 : 0) + h;   // W1 (128,64) row-major
        float a0 = sel ? 0.f : b1[h], a1 = 0.f;
        #pragma unroll
        for (int k = 0; k < 64; k += 2) {
            a0 = fmaf(z[k],     w[k * 64],       a0);
            a1 = fmaf(z[k + 1], w[(k + 1) * 64], a1);
        }
        unsigned short val = h_bits(a0 + a1);   // fp32-exact matmul, one RNE to fp16
        int s = h >> 5, q = (h >> 3) & 3, e = h & 7;
        if (sel) {
            Bph[n * 64 + q * 16 + s * 8 + e] = val;
        } else {
            Aph[(n >> 4) * 1024 + (q * 16 + (n & 15)) * 16 + s * 8 + e] = val;
        }
    } else {
        int tt = (blockIdx.x - 512) * 256 + threadIdx.x;   // 0..511
        int f = tt >> 6, lane = tt & 63;                   // f = s*4 + t, 8 frags
        int s = f >> 2, t4 = f & 3, q = lane >> 4, l15 = lane & 15;
        int n = t4 * 16 + l15;
        unsigned w4[4];
        #pragma unroll
        for (int p = 0; p < 4; ++p) {
            int k = s * 32 + q * 8 + 2 * p;
            unsigned lo = h_bits(W2[k * 64 + n]);
            unsigned hi = h_bits(W2[(k + 1) * 64 + n]);
            w4[p] = lo | (hi << 16);
        }
        W2h[f * 64 + lane] = make_uint4(w4[0], w4[1], w4[2], w4[3]);
    }
}

// ---- main: 1024 blocks x 256 thr; block = row i, each wave 16 j-tiles of 16
// processed as TWO GROUPS of 8 (psum[8] reused -> register footprint identical to
// R15's proven-fit config). Whole row in one block: Srow[i] is a PLAIN STORE after
// an LDS reduce (zero atomics in main). All co-resident blocks read the identical
// Aph stream in the same order -> L1 hits.
// __launch_bounds__(256, 4) is LOAD-BEARING: unified VGPR+AGPR footprint measured
// in (102, 128] (R7 fits at budget 128; R13 spills at 102; R11 spills at 85).
// Any min-waves bound > 4 forces a 100+ MB scratch spill. Do not raise.
// No fences / ordered atomics anywhere (R3, R10: TCC cache-maintenance storms).
__global__ void __launch_bounds__(256, 4)
main_kernel(const unsigned short* __restrict__ Aph, const unsigned short* __restrict__ Bph,
            const uint4* __restrict__ W2h,
            const float* __restrict__ b2, const float* __restrict__ Wo,
            float* __restrict__ Srow, float* __restrict__ T0row) {
    const int i    = blockIdx.x;
    const int tid  = threadIdx.x;
    const int lane = tid & 63;
    const int wave = tid >> 6;
    const int l15  = lane & 15;
    const int q    = lane >> 4;

    __shared__ uint4 sW[512];      // W2 frag bits, 8 KB
    __shared__ float sb2[64];      // b2, 256 B
    __shared__ float sWo[64];      // Wo, 256 B
    __shared__ float sS[4];        // per-wave exp-sum partials

    // cooperative stage: 2 x 16B VMEM per thread + tiny b2/Wo copy
    sW[tid]       = W2h[tid];
    sW[tid + 256] = W2h[tid + 256];
    if (tid < 64)                  sb2[tid]      = b2[tid];
    else if (tid < 128)            sWo[tid - 64] = Wo[tid - 64];
    __syncthreads();

    // W2 fragments from LDS: 8 ds_read_b128, lane-contiguous (conflict-free)
    half8 W[2][4];   // [s][t]
    #pragma unroll
    for (int f = 0; f < 8; ++f) {
        H8U u; u.u = sW[f * 64 + lane];
        W[f >> 2][f & 3] = u.h;
    }

    // B_i per-lane slice (fp16 frag order): 2 dwordx4 = 16 halves, k = s*32+q*8+e
    H8U cb0, cb1;
    {
        const uint4* bp = (const uint4*)(Bph + i * 64 + q * 16);
        cb0.u = bp[0];
        cb1.u = bp[1];
    }

    // b2 folded into acc init; Wo per-lane, element (t,r) is h = t*16 + q*4 + r
    f32x4 b2v[4];
    float wov[4][4];
    #pragma unroll
    for (int t = 0; t < 4; ++t) {
        float4 bt = *(const float4*)(sb2 + t * 16 + q * 4);
        float4 wt = *(const float4*)(sWo + t * 16 + q * 4);
        b2v[t] = (f32x4){bt.x, bt.y, bt.z, bt.w};
        wov[t][0] = wt.x; wov[t][1] = wt.y; wov[t][2] = wt.z; wov[t][3] = wt.w;
    }

    const half8 zero = {0, 0, 0, 0, 0, 0, 0, 0};
    float sacc = 0.f;

    // Two groups of 8 tiles; psum[8] reused -> no register growth vs R15.
    #pragma unroll
    for (int g = 0; g < 2; ++g) {
        const int tbase = wave * 16 + g * 8;
        const unsigned short* ap = Aph + tbase * 1024 + lane * 16;

        H8U x0, x1;
        x0.u = ((const uint4*)ap)[0];
        x1.u = ((const uint4*)ap)[1];

        float psum[8];

        #pragma unroll
        for (int tile = 0; tile < 8; ++tile) {
            half8 a0 = __builtin_elementwise_max(x0.h + cb0.h, zero);   // k 0..31
            half8 a1 = __builtin_elementwise_max(x1.h + cb1.h, zero);   // k 32..63
            if (tile < 7) {
                const uint4* nx = (const uint4*)(ap + (tile + 1) * 1024);
                x0.u = nx[0];
                x1.u = nx[1];
            }

            f32x4 acc[4];
            #pragma unroll
            for (int t = 0; t < 4; ++t) acc[t] = b2v[t];
            #pragma unroll
            for (int t = 0; t < 4; ++t) {
                acc[t] = __builtin_amdgcn_mfma_f32_16x16x32_f16(W[0][t], a0, acc[t], 0, 0, 0);
                acc[t] = __builtin_amdgcn_mfma_f32_16x16x32_f16(W[1][t], a1, acc[t], 0, 0, 0);
            }

            float p0 = 0.f, p1 = 0.f, p2 = 0.f, p3 = 0.f;
            #pragma unroll
            for (int t = 0; t < 4; ++t) {
                p0 = fmaf(fmaxf(acc[t][0], 0.f), wov[t][0], p0);
                p1 = fmaf(fmaxf(acc[t][1], 0.f), wov[t][1], p1);
                p2 = fmaf(fmaxf(acc[t][2], 0.f), wov[t][2], p2);
                p3 = fmaf(fmaxf(acc[t][3], 0.f), wov[t][3], p3);
            }
            psum[tile] = (p0 + p1) + (p2 + p3);
        }

        // Epilogue for this group: 8 independent reduce/exp chains
        #pragma unroll
        for (int tile = 0; tile < 8; ++tile) {
            float ps = psum[tile];
            ps += __shfl_xor(ps, 16);
            ps += __shfl_xor(ps, 32);   // T1[j], replicated over the 4 q-groups
            const int j = (tbase + tile) * 16 + l15;
            if (j == i && q == 0) T0row[i] = ps;   // diagonal: exactly one writer
            sacc += __expf(ps);
        }
    }

    // reduce over l15 only (q-groups are exact replicas -> exact sum)
    sacc += __shfl_xor(sacc, 1);
    sacc += __shfl_xor(sacc, 2);
    sacc += __shfl_xor(sacc, 4);
    sacc += __shfl_xor(sacc, 8);
    if (lane == 0) sS[wave] = sacc;
    __syncthreads();
    if (tid == 0)
        Srow[i] = (sS[0] + sS[1]) + (sS[2] + sS[3]);   // plain store: whole row here
}

// ---- combine+finish: 1 block x 1024 thr. bound = mean(T0) - (mean(log Srow) - ln N)
__global__ void __launch_bounds__(1024)
combine_finish(const float* __restrict__ Srow, const float* __restrict__ T0row,
               float* __restrict__ out) {
    int i = threadIdx.x;
    float l  = logf(Srow[i]);
    float t0 = T0row[i];
    #pragma unroll
    for (int off = 1; off < 64; off <<= 1) {
        l  += __shfl_xor(l, off);
        t0 += __shfl_xor(t0, off);
    }
    __shared__ float sl[16], st[16];
    int w = threadIdx.x >> 6;
    if ((threadIdx.x & 63) == 0) { sl[w] = l; st[w] = t0; }
    __syncthreads();
    if (threadIdx.x == 0) {
        float L = 0.f, T = 0.f;
        #pragma unroll
        for (int k = 0; k < 16; ++k) { L += sl[k]; T += st[k]; }
        out[0] = (T - L) * (1.0f / 1024.0f) + 6.9314718055994531f;
    }
}

extern "C" void kernel_launch(void* const* d_in, const int* in_sizes, int n_in,
                              void* d_out, int out_size, void* d_ws, size_t ws_size,
                              hipStream_t stream) {
    const float* z_c = (const float*)d_in[0];
    const float* z_d = (const float*)d_in[1];
    const float* W1  = (const float*)d_in[2];
    const float* b1  = (const float*)d_in[3];
    const float* W2  = (const float*)d_in[4];
    const float* b2  = (const float*)d_in[5];
    const float* Wo  = (const float*)d_in[6];
    // d_in[7] = bo: shifts T0.mean and every LSE equally -> cancels; omitted.
    float* out   = (float*)d_out;

    unsigned short* Aph = (unsigned short*)d_ws;   // 65536 fp16 (128 KB), frag-order
    unsigned short* Bph = Aph + NN * 64;           // 65536 fp16 (128 KB), frag-order
    uint4* W2h   = (uint4*)(Bph + NN * 64);        // 512 uint4 (8 KB)
    float* Srow  = (float*)(W2h + 512);            // 1024 fp32 (plain-stored by main)
    float* T0row = Srow + NN;                      // 1024 fp32

    prep_kernel<<<514, 256, 0, stream>>>(z_c, z_d, W1, b1, W2, Aph, Bph, W2h);
    main_kernel<<<1024, 256, 0, stream>>>(Aph, Bph, W2h, b2, Wo, Srow, T0row);
    combine_finish<<<1, 1024, 0, stream>>>(Srow, T0row, out);
}